// Round 2
// baseline (531.098 us; speedup 1.0000x reference)
//
#include <hip/hip_runtime.h>

// Problem constants
#define M_TOT   16384      // 8*2048 rows
#define DM      1024       // d_model
#define CD      64         // code_depth
#define NCODES  8192
#define NCHUNK  16         // code-chunks for dist/argmin
#define CPC     (NCODES / NCHUNK)   // 512 codes per chunk

// Output layout (fp32, concatenated in return order)
#define SOFT_OFF  0
#define IDX_OFF   1048576            // 16384*64
#define HARD_OFF  1064960            // + 16384
#define LOSS_OFF  2113536            // + 16384*64

// ---------------------------------------------------------------------------
// Kernel 0: c2[k] = ||book_k||^2
// ---------------------------------------------------------------------------
__global__ __launch_bounds__(256) void compute_c2(const float* __restrict__ book,
                                                  float* __restrict__ c2) {
    const int k = blockIdx.x * 256 + threadIdx.x;
    const float4* p = (const float4*)(book + (size_t)k * CD);
    float s = 0.0f;
#pragma unroll
    for (int q = 0; q < CD / 4; ++q) {
        const float4 v = p[q];
        s = fmaf(v.x, v.x, s);
        s = fmaf(v.y, v.y, s);
        s = fmaf(v.z, v.z, s);
        s = fmaf(v.w, v.w, s);
    }
    c2[k] = s;
}

// ---------------------------------------------------------------------------
// Kernel 1: soft partial GEMM: dst[row][col] (+bias) = x[row][k0..] @ W[col][k0..]
// 64 rows x 64 cols per block, 256 threads, 4x4 per thread, BK=32.
// blockIdx.y selects the K-chunk; bias==nullptr for split-K partials.
// ---------------------------------------------------------------------------
__global__ __launch_bounds__(256) void soft_gemm_k(const float* __restrict__ x,
                                                   const float* __restrict__ W,
                                                   const float* __restrict__ bias,
                                                   float* __restrict__ dst,
                                                   int kchunk) {
    __shared__ float xt[32][68];  // xt[kk][row]
    __shared__ float wt[32][68];  // wt[kk][col]

    const int tid = threadIdx.x;
    const int r0  = blockIdx.x * 64;
    const int k0base = blockIdx.y * kchunk;
    const int cg  = tid & 15;   // col group: cols cg*4..+3
    const int rg  = tid >> 4;   // row group: rows rg*4..+3

    float acc[4][4] = {};

    for (int k0 = k0base; k0 < k0base + kchunk; k0 += 32) {
#pragma unroll
        for (int i = 0; i < 2; ++i) {
            const int f   = tid + i * 256;       // 0..511
            const int row = f >> 3;              // 0..63
            const int kq  = (f & 7) * 4;         // 0..28
            const float4 v = *(const float4*)(x + (size_t)(r0 + row) * DM + k0 + kq);
            xt[kq + 0][row] = v.x; xt[kq + 1][row] = v.y;
            xt[kq + 2][row] = v.z; xt[kq + 3][row] = v.w;
            const float4 w = *(const float4*)(W + (size_t)row * DM + k0 + kq); // row == col index
            wt[kq + 0][row] = w.x; wt[kq + 1][row] = w.y;
            wt[kq + 2][row] = w.z; wt[kq + 3][row] = w.w;
        }
        __syncthreads();
#pragma unroll 8
        for (int kk = 0; kk < 32; ++kk) {
            const float4 xv = *(const float4*)&xt[kk][rg * 4];
            const float4 wv = *(const float4*)&wt[kk][cg * 4];
            const float xa[4] = {xv.x, xv.y, xv.z, xv.w};
            const float wa[4] = {wv.x, wv.y, wv.z, wv.w};
#pragma unroll
            for (int r = 0; r < 4; ++r)
#pragma unroll
                for (int q = 0; q < 4; ++q)
                    acc[r][q] = fmaf(xa[r], wa[q], acc[r][q]);
        }
        __syncthreads();
    }

    float4 bb = make_float4(0.f, 0.f, 0.f, 0.f);
    if (bias) bb = *(const float4*)(bias + cg * 4);
    float* base = dst + (size_t)blockIdx.y * M_TOT * CD;
#pragma unroll
    for (int r = 0; r < 4; ++r) {
        float4 o;
        o.x = acc[r][0] + bb.x; o.y = acc[r][1] + bb.y;
        o.z = acc[r][2] + bb.z; o.w = acc[r][3] + bb.w;
        *(float4*)(base + (size_t)(r0 + rg * 4 + r) * CD + cg * 4) = o;
    }
}

// ---------------------------------------------------------------------------
// Kernel 1b: reduce split-K partials + bias -> out_soft (deterministic order)
// one float4 per thread; grid covers M_TOT*CD/4 = 262144 quads
// ---------------------------------------------------------------------------
__global__ __launch_bounds__(256) void soft_reduce(const float* __restrict__ partial,
                                                   const float* __restrict__ bias,
                                                   float* __restrict__ out_soft,
                                                   int nsplit) {
    const int i = blockIdx.x * 256 + threadIdx.x;   // float4 index
    const float4* p = (const float4*)partial;
    float4 s = p[i];
    for (int j = 1; j < nsplit; ++j) {
        const float4 v = p[(size_t)j * (M_TOT * CD / 4) + i];
        s.x += v.x; s.y += v.y; s.z += v.z; s.w += v.w;
    }
    const float4 bb = ((const float4*)bias)[i & 15];   // CD/4 = 16 quads per row
    s.x += bb.x; s.y += bb.y; s.z += bb.z; s.w += bb.w;
    ((float4*)out_soft)[i] = s;
}

// ---------------------------------------------------------------------------
// Kernel 2: per-row argmin_k of (c2[k] - 2*soft.book_k), no LDS.
// Each thread owns one row (soft[64] in VGPRs); k is wave-uniform so
// book/c2 loads scalarize to s_load (broadcast via scalar cache).
// grid: (64 row-blocks, NCHUNK code-chunks), 256 threads.
// ---------------------------------------------------------------------------
__global__ __launch_bounds__(256) void dist_argmin2(const float* __restrict__ soft,
                                                    const float* __restrict__ book,
                                                    const float* __restrict__ c2,
                                                    float* __restrict__ cand_d,
                                                    int* __restrict__ cand_i) {
    const int row   = blockIdx.x * 256 + threadIdx.x;
    const int kbase = blockIdx.y * CPC;

    float4 s4[16];
    const float4* sp = (const float4*)(soft + (size_t)row * CD);
#pragma unroll
    for (int q = 0; q < 16; ++q) s4[q] = sp[q];

    float mind = 3.4e38f;
    int   mini = kbase;
    const float4* bp = (const float4*)(book + (size_t)kbase * CD);

    for (int kk = 0; kk < CPC; kk += 4) {
        const float4* b0 = bp + (size_t)(kk + 0) * 16;
        const float4* b1 = bp + (size_t)(kk + 1) * 16;
        const float4* b2 = bp + (size_t)(kk + 2) * 16;
        const float4* b3 = bp + (size_t)(kk + 3) * 16;
        float a0 = 0.f, a1 = 0.f, a2 = 0.f, a3 = 0.f;
#pragma unroll
        for (int q = 0; q < 16; ++q) {
            const float4 sv = s4[q];
            const float4 v0 = b0[q];
            a0 = fmaf(sv.x, v0.x, a0); a0 = fmaf(sv.y, v0.y, a0);
            a0 = fmaf(sv.z, v0.z, a0); a0 = fmaf(sv.w, v0.w, a0);
            const float4 v1 = b1[q];
            a1 = fmaf(sv.x, v1.x, a1); a1 = fmaf(sv.y, v1.y, a1);
            a1 = fmaf(sv.z, v1.z, a1); a1 = fmaf(sv.w, v1.w, a1);
            const float4 v2 = b2[q];
            a2 = fmaf(sv.x, v2.x, a2); a2 = fmaf(sv.y, v2.y, a2);
            a2 = fmaf(sv.z, v2.z, a2); a2 = fmaf(sv.w, v2.w, a2);
            const float4 v3 = b3[q];
            a3 = fmaf(sv.x, v3.x, a3); a3 = fmaf(sv.y, v3.y, a3);
            a3 = fmaf(sv.z, v3.z, a3); a3 = fmaf(sv.w, v3.w, a3);
        }
        const int k = kbase + kk;
        const float d0 = fmaf(-2.f, a0, c2[k + 0]);
        const float d1 = fmaf(-2.f, a1, c2[k + 1]);
        const float d2 = fmaf(-2.f, a2, c2[k + 2]);
        const float d3 = fmaf(-2.f, a3, c2[k + 3]);
        // ascending k, strict < -> first-index-wins ties (matches np.argmin)
        if (d0 < mind) { mind = d0; mini = k + 0; }
        if (d1 < mind) { mind = d1; mini = k + 1; }
        if (d2 < mind) { mind = d2; mini = k + 2; }
        if (d3 < mind) { mind = d3; mini = k + 3; }
    }

    cand_d[blockIdx.y * M_TOT + row] = mind;
    cand_i[blockIdx.y * M_TOT + row] = mini;
}

// ---------------------------------------------------------------------------
// Kernel 3: combine NCHUNK candidates, gather hard, write idx/ste, losses.
// block = 256 threads = 16 rows x 16 (chunk / dim-quad) lanes
// ---------------------------------------------------------------------------
__global__ __launch_bounds__(256) void finalize(const float* __restrict__ book,
                                                const float* __restrict__ cand_d,
                                                const int* __restrict__ cand_i,
                                                float* __restrict__ out) {
    __shared__ float rd[256];
    __shared__ int   ri[256];
    __shared__ int   ksels[16];
    __shared__ float red[256];

    const int tid  = threadIdx.x;
    const int rloc = tid >> 4;          // 0..15
    const int g    = tid & 15;          // chunk index / dim-quad
    const int row  = blockIdx.x * 16 + rloc;

    rd[tid] = cand_d[(size_t)g * M_TOT + row];
    ri[tid] = cand_i[(size_t)g * M_TOT + row];
    __syncthreads();

    if (g == 0) {
        float bd = rd[rloc * 16];
        int   bi = ri[rloc * 16];
#pragma unroll
        for (int j = 1; j < 16; ++j) {
            const float dd = rd[rloc * 16 + j];
            if (dd < bd) { bd = dd; bi = ri[rloc * 16 + j]; } // ascending chunk => first-wins
        }
        ksels[rloc] = bi;
        out[IDX_OFF + row] = (float)bi;
    }
    __syncthreads();

    const int k  = ksels[rloc];
    const int dq = g * 4;

    const float4 h = *(const float4*)(book + (size_t)k * CD + dq);
    const float4 s = *(const float4*)(out + SOFT_OFF + (size_t)row * CD + dq);

    const float dx = h.x - s.x, dy = h.y - s.y, dz = h.z - s.z, dw = h.w - s.w;
    float4 ste;  // mirror ref expression soft + (hard - soft)
    ste.x = s.x + dx; ste.y = s.y + dy; ste.z = s.z + dz; ste.w = s.w + dw;
    *(float4*)(out + HARD_OFF + (size_t)row * CD + dq) = ste;

    red[tid] = dx * dx + dy * dy + dz * dz + dw * dw;
    __syncthreads();
#pragma unroll
    for (int sh = 128; sh > 0; sh >>= 1) {
        if (tid < sh) red[tid] += red[tid + sh];
        __syncthreads();
    }
    if (tid == 0) {
        const float v = red[0] * (1.0f / (float)(M_TOT * CD));
        atomicAdd(out + LOSS_OFF, v);      // commitment
        atomicAdd(out + LOSS_OFF + 1, v);  // embedding (numerically identical)
    }
}

// ---------------------------------------------------------------------------
extern "C" void kernel_launch(void* const* d_in, const int* in_sizes, int n_in,
                              void* d_out, int out_size, void* d_ws, size_t ws_size,
                              hipStream_t stream) {
    const float* x    = (const float*)d_in[0];
    const float* W    = (const float*)d_in[1];
    const float* bias = (const float*)d_in[2];
    const float* book = (const float*)d_in[3];  // [1][8192][64] == flat [8192][64]
    float* out = (float*)d_out;

    float* ws     = (float*)d_ws;
    float* c2     = ws;                                   // 8192 floats
    float* cand_d = ws + NCODES;                          // NCHUNK*16384 floats
    int*   cand_i = (int*)(cand_d + NCHUNK * M_TOT);      // NCHUNK*16384 ints
    float* partial = (float*)(cand_i + NCHUNK * M_TOT);   // splitk*M_TOT*CD floats

    const size_t base_floats = NCODES + (size_t)2 * NCHUNK * M_TOT;
    int splitk = 4;
    if (ws_size < (base_floats + (size_t)splitk * M_TOT * CD) * sizeof(float))
        splitk = 1;

    compute_c2<<<NCODES / 256, 256, 0, stream>>>(book, c2);

    if (splitk == 4) {
        soft_gemm_k<<<dim3(M_TOT / 64, 4), 256, 0, stream>>>(x, W, nullptr, partial, DM / 4);
        soft_reduce<<<M_TOT * CD / 4 / 256, 256, 0, stream>>>(partial, bias, out + SOFT_OFF, 4);
    } else {
        soft_gemm_k<<<dim3(M_TOT / 64, 1), 256, 0, stream>>>(x, W, bias, out + SOFT_OFF, DM);
    }

    dist_argmin2<<<dim3(M_TOT / 256, NCHUNK), 256, 0, stream>>>(out + SOFT_OFF, book, c2,
                                                                cand_d, cand_i);
    hipMemsetAsync(out + LOSS_OFF, 0, 2 * sizeof(float), stream);
    finalize<<<M_TOT / 16, 256, 0, stream>>>(book, cand_d, cand_i, out);
}